// Round 13
// baseline (59.090 us; speedup 1.0000x reference)
//
#include <hip/hip_runtime.h>

typedef _Float16 f16x4 __attribute__((ext_vector_type(4)));
typedef __fp16 fp16x2 __attribute__((ext_vector_type(2)));   // cvt_pkrtz return type
typedef float f32x4 __attribute__((ext_vector_type(4)));

#define NBUCKETS 256
#define WT_OFF 1024          // weight-frag table offset in d_ws (bytes)
#define SSTR 148             // row stride in halves = 74 words; gcd(74,32)=2 -> free 2-way b64
#define NROWS 42             // staged rows (32 outputs + 10 halo)
#define NCH 36               // float4 chunks per row (144 cols >= 128+10 halo + frag overread)

// ---- pre-kernel: zero buckets + build shared weight fragment ----
// Banded, translation-invariant: wf[kk][j] = w1[4g + j + 16kk - ln] (0 outside band).
// Serves as horizontal B-frag AND vertical A-frag for all tiles (validated R3/R5-R12).
__global__ void ssim_pre(const float* __restrict__ win, float* __restrict__ ws)
{
    int lane = threadIdx.x;            // 64 threads
#pragma unroll
    for (int i = 0; i < 4; ++i) ws[lane + 64 * i] = 0.f;   // zero buckets

    float w1[11];
#pragma unroll
    for (int i = 0; i < 11; ++i) {
        float s = 0.f;
#pragma unroll
        for (int j = 0; j < 11; ++j) s += win[i * 11 + j];
        w1[i] = s;                     // 1D gaussian (row sums; sum==1)
    }
    int g = lane >> 4, ln = lane & 15;
    _Float16* wt = (_Float16*)((char*)ws + WT_OFF) + lane * 8;
#pragma unroll
    for (int kk = 0; kk < 2; ++kk)
#pragma unroll
        for (int j = 0; j < 4; ++j) {
            int idx = 4 * g + j + 16 * kk - ln;
            wt[kk * 4 + j] = (_Float16)((idx >= 0 && idx < 11) ? w1[idx] : 0.f);
        }
}

__device__ __forceinline__ f16x4 cvt4(f32x4 a)
{
    union { fp16x2 h2[2]; f16x4 f; } u;
    u.h2[0] = __builtin_amdgcn_cvt_pkrtz(a[0], a[1]);
    u.h2[1] = __builtin_amdgcn_cvt_pkrtz(a[2], a[3]);
    return u.f;
}

// ---- main: 128x32 output region per block, 8 waves, ONE 16x32 strip per wave.
// ONE barrier; H fragments register-resident (mfma D-frag == B-frag layout).
// Quantities: mu1, mu2, A=conv((r+d)^2), B=conv((r-d)^2).
// 512-thread blocks -> 4 blocks x 8 waves = 32 waves/CU (thread-cap bound).
__global__ __launch_bounds__(512, 8) void ssim_main(
    const float* __restrict__ raw, const float* __restrict__ dst,
    const float* __restrict__ ws_ro, float* __restrict__ buckets)
{
    __shared__ __align__(16) _Float16 sr[NROWS * SSTR];
    __shared__ __align__(16) _Float16 sd[NROWS * SSTR];

    const int tid = threadIdx.x;
    const int wv = tid >> 6;           // 0..7 = this wave's 16-wide x-strip
    const int lane = tid & 63;
    const int g = lane >> 4;
    const int ln = lane & 15;
    const int nt = wv;

    const int gx0 = blockIdx.x * 128;
    const int gy0 = blockIdx.y * 32;
    const long ioff = (long)blockIdx.z * (512 * 512);
    const float* rb = raw + ioff;
    const float* db = dst + ioff;

    const _Float16* wt = (const _Float16*)((const char*)ws_ro + WT_OFF) + lane * 8;
    f16x4 wf0 = *(const f16x4*)(wt);
    f16x4 wf1 = *(const f16x4*)(wt + 4);

    // ---- staging: 3024 tasks = 42 rows x {r,d} x 36 float4 chunks, clamped.
    // Phase 1: issue ALL loads (max MLP). Phase 2: pack f32->f16, write LDS.
    // Clamped halo junk is finite and only meets zero band-weights / dropped outputs.
    float4 fv[6];
#pragma unroll
    for (int k = 0; k < 6; ++k) {
        int t = tid + 512 * k;
        if (k < 5 || t < 3024) {
            int chunk = t % NCH;
            int sub = t / NCH;         // 0..83
            int row = sub >> 1;        // 0..41
            int gy = gy0 + row; if (gy > 511) gy = 511;
            int gxc = gx0 + 4 * chunk; if (gxc > 508) gxc = 508;
            const float* src = (sub & 1) ? db : rb;
            fv[k] = *reinterpret_cast<const float4*>(src + (long)gy * 512 + gxc);
        }
    }
#pragma unroll
    for (int k = 0; k < 6; ++k) {
        int t = tid + 512 * k;
        if (k < 5 || t < 3024) {
            int chunk = t % NCH;
            int sub = t / NCH;
            int row = sub >> 1;
            _Float16* dstp = ((sub & 1) ? sd : sr) + row * SSTR + chunk * 4;
            union { fp16x2 h2[2]; uint2 u; } pk;
            pk.h2[0] = __builtin_amdgcn_cvt_pkrtz(fv[k].x, fv[k].y);
            pk.h2[1] = __builtin_amdgcn_cvt_pkrtz(fv[k].z, fv[k].w);
            *reinterpret_cast<uint2*>(dstp) = pk.u;
        }
    }
    __syncthreads();

    // ---- horizontal conv -> register f16 frags (4 quantities) ----
    f16x4 hf0[4], hf1[4], hf2[4];
#define COMP_H(HF, MT)                                                        \
    {                                                                         \
        f32x4 a0 = {0,0,0,0}, a1 = {0,0,0,0}, a2 = {0,0,0,0}, a3 = {0,0,0,0}; \
        int rrow = ln + 16 * (MT); if (rrow > 41) rrow = 41;                  \
        const _Float16* pr = sr + rrow * SSTR + 16 * nt + 4 * g;              \
        const _Float16* pd = sd + rrow * SSTR + 16 * nt + 4 * g;              \
        _Pragma("unroll")                                                     \
        for (int kk = 0; kk < 2; ++kk) {                                      \
            f16x4 rA = *(const f16x4*)(pr + 16 * kk);                         \
            f16x4 dA = *(const f16x4*)(pd + 16 * kk);                         \
            f16x4 wf = kk ? wf1 : wf0;                                        \
            f16x4 sA = rA + dA, qA = rA - dA;                                 \
            f16x4 ss = sA * sA, qq = qA * qA;                                 \
            a0 = __builtin_amdgcn_mfma_f32_16x16x16f16(rA, wf, a0, 0, 0, 0);  \
            a1 = __builtin_amdgcn_mfma_f32_16x16x16f16(dA, wf, a1, 0, 0, 0);  \
            a2 = __builtin_amdgcn_mfma_f32_16x16x16f16(ss, wf, a2, 0, 0, 0);  \
            a3 = __builtin_amdgcn_mfma_f32_16x16x16f16(qq, wf, a3, 0, 0, 0);  \
        }                                                                     \
        HF[0] = cvt4(a0); HF[1] = cvt4(a1); HF[2] = cvt4(a2); HF[3] = cvt4(a3); \
    }
    COMP_H(hf0, 0)
    COMP_H(hf1, 1)
    COMP_H(hf2, 2)
#undef COMP_H

    // ---- vertical conv + SSIM epilogue (registers only) ----
    float lsum = 0.f;
    const int ox = gx0 + 16 * nt + ln;
#define COMP_O(HA, HB, MTV)                                                   \
    {                                                                         \
        f32x4 z = {0, 0, 0, 0};                                               \
        f32x4 v0 = __builtin_amdgcn_mfma_f32_16x16x16f16(wf0, HA[0], z, 0, 0, 0); \
        f32x4 v1 = __builtin_amdgcn_mfma_f32_16x16x16f16(wf0, HA[1], z, 0, 0, 0); \
        f32x4 v2 = __builtin_amdgcn_mfma_f32_16x16x16f16(wf0, HA[2], z, 0, 0, 0); \
        f32x4 v3 = __builtin_amdgcn_mfma_f32_16x16x16f16(wf0, HA[3], z, 0, 0, 0); \
        v0 = __builtin_amdgcn_mfma_f32_16x16x16f16(wf1, HB[0], v0, 0, 0, 0);  \
        v1 = __builtin_amdgcn_mfma_f32_16x16x16f16(wf1, HB[1], v1, 0, 0, 0);  \
        v2 = __builtin_amdgcn_mfma_f32_16x16x16f16(wf1, HB[2], v2, 0, 0, 0);  \
        v3 = __builtin_amdgcn_mfma_f32_16x16x16f16(wf1, HB[3], v3, 0, 0, 0);  \
        int oy0 = gy0 + 16 * (MTV) + 4 * g;                                   \
        if (ox < 502) {                                                       \
            _Pragma("unroll")                                                 \
            for (int j = 0; j < 4; ++j) {                                     \
                if (oy0 + j < 502) {                                          \
                    float m1 = v0[j], m2 = v1[j], A = v2[j], B = v3[j];       \
                    float m1s = m1 * m1, m2s = m2 * m2, m12 = m1 * m2;        \
                    float num = (2.f * m12 + 6.5025f) *                       \
                                (0.5f * (A - B) - 2.f * m12 + 58.5225f);      \
                    float den = (m1s + m2s + 6.5025f) *                       \
                                (0.5f * (A + B) - m1s - m2s + 58.5225f);      \
                    lsum += __fdividef(num, den);                             \
                }                                                             \
            }                                                                 \
        }                                                                     \
    }
    COMP_O(hf0, hf1, 0)
    COMP_O(hf1, hf2, 1)
#undef COMP_O

    // per-wave reduce + scattered atomic (no fences, no extra barrier)
#pragma unroll
    for (int off = 32; off; off >>= 1) lsum += __shfl_down(lsum, off);
    if (lane == 0) {
        int bucket = ((blockIdx.x + (blockIdx.y << 2) + blockIdx.z * 67) * 8 + wv) & (NBUCKETS - 1);
        atomicAdd(&buckets[bucket], lsum);
    }
}

__global__ void ssim_finalize(const float* __restrict__ buckets,
                              float* __restrict__ out, float inv)
{
    int t = threadIdx.x;
    float s = 0.f;
    for (int i = t; i < NBUCKETS; i += 64) s += buckets[i];
#pragma unroll
    for (int off = 32; off; off >>= 1) s += __shfl_down(s, off);
    if (t == 0) out[0] = s * inv;
}

extern "C" void kernel_launch(void* const* d_in, const int* in_sizes, int n_in,
                              void* d_out, int out_size, void* d_ws, size_t ws_size,
                              hipStream_t stream) {
    const float* raw = (const float*)d_in[0];
    const float* dst = (const float*)d_in[1];
    const float* win = (const float*)d_in[2];
    float* out = (float*)d_out;
    float* ws = (float*)d_ws;

    int nimg = in_sizes[0] / (512 * 512);     // B*C = 48
    float inv = 1.0f / ((float)nimg * 502.f * 502.f);

    ssim_pre<<<1, 64, 0, stream>>>(win, ws);
    dim3 grid(4, 16, nimg);                   // 128-wide x-region, 32-tall y-tile, image
    ssim_main<<<grid, 512, 0, stream>>>(raw, dst, ws, ws);
    ssim_finalize<<<1, 64, 0, stream>>>(ws, out, inv);
}

// Round 14
// 39.878 us; speedup vs baseline: 1.4818x; 1.4818x over previous
//
#include <hip/hip_runtime.h>

typedef _Float16 f16x4 __attribute__((ext_vector_type(4)));
typedef _Float16 f16x8 __attribute__((ext_vector_type(8)));
typedef __fp16 fp16x2 __attribute__((ext_vector_type(2)));   // cvt_pkrtz return type
typedef float f32x4 __attribute__((ext_vector_type(4)));
typedef float f32x2 __attribute__((ext_vector_type(2)));

#define NBUCKETS 256
#define WT_OFF 1024          // weight-frag table offset in d_ws (bytes)
#define SSTR 88              // row stride in halves (16B-aligned rows for b128; uniform bank use)
#define NLD 13               // staging float4 loads per thread (3200/256 = 12.5)

// ---- pre-kernel: zero buckets + per-lane weight fragments ----
// Banded, translation-invariant. Per lane (g=lane>>4, ln=lane&15), 16 halves:
//  [0..7]  vertical pair for 16x16x16: wf[kk*4+j] = w1[4g+j+16kk - ln]
//  [8..15] horizontal for 16x16x32:    wh[j]      = w1[8g+j - ln]
__global__ void ssim_pre(const float* __restrict__ win, float* __restrict__ ws)
{
    int lane = threadIdx.x;            // 64 threads
#pragma unroll
    for (int i = 0; i < 4; ++i) ws[lane + 64 * i] = 0.f;   // zero buckets

    float w1[11];
#pragma unroll
    for (int i = 0; i < 11; ++i) {
        float s = 0.f;
#pragma unroll
        for (int j = 0; j < 11; ++j) s += win[i * 11 + j];
        w1[i] = s;                     // 1D gaussian (row sums; sum==1)
    }
    int g = lane >> 4, ln = lane & 15;
    _Float16* wt = (_Float16*)((char*)ws + WT_OFF) + lane * 16;
#pragma unroll
    for (int kk = 0; kk < 2; ++kk)
#pragma unroll
        for (int j = 0; j < 4; ++j) {
            int idx = 4 * g + j + 16 * kk - ln;
            wt[kk * 4 + j] = (_Float16)((idx >= 0 && idx < 11) ? w1[idx] : 0.f);
        }
#pragma unroll
    for (int j = 0; j < 8; ++j) {
        int idx = 8 * g + j - ln;
        wt[8 + j] = (_Float16)((idx >= 0 && idx < 11) ? w1[idx] : 0.f);
    }
}

__device__ __forceinline__ f16x4 cvt4(f32x4 a)
{
    union { fp16x2 h2[2]; f16x4 f; } u;
    u.h2[0] = __builtin_amdgcn_cvt_pkrtz(a[0], a[1]);
    u.h2[1] = __builtin_amdgcn_cvt_pkrtz(a[2], a[3]);
    return u.f;
}

// ---- main: 64x64 output region per block (2 x 64x32 tiles), 4 waves, ONE barrier.
// H-pass: one mfma_f32_16x16x32_f16 per quantity (b128 frag reads); D-frag (row=4g+j)
// feeds vertical 16x16x16 B-frags directly in registers (validated R3/R5-R12).
// Quantities: mu1, mu2, A=conv((r+d)^2), B=conv((r-d)^2).
__global__ __launch_bounds__(256, 4) void ssim_main(
    const float* __restrict__ raw, const float* __restrict__ dst,
    const float* __restrict__ ws_ro, float* __restrict__ buckets)
{
    __shared__ __align__(16) _Float16 sr[80 * SSTR];
    __shared__ __align__(16) _Float16 sd[80 * SSTR];

    const int tid = threadIdx.x;
    const int wv = tid >> 6;           // wave = 16-wide x-strip
    const int lane = tid & 63;
    const int g = lane >> 4;
    const int ln = lane & 15;
    const int nt = wv;

    const int gx0 = blockIdx.x * 64;
    const int ybase32 = blockIdx.y * 64;        // first input row of the region
    const long ioff = (long)blockIdx.z * (512 * 512);
    const float* rb = raw + ioff;
    const float* db = dst + ioff;

    const _Float16* wt = (const _Float16*)((const char*)ws_ro + WT_OFF) + lane * 16;
    f16x4 wf0 = *(const f16x4*)(wt);
    f16x4 wf1 = *(const f16x4*)(wt + 4);
    f16x8 wh  = *(const f16x8*)(wt + 8);

    // ---- staging: 80 rows x {r,d} x 20 float4 chunks = 3200 tasks.
    // Phase 1: issue ALL loads (max MLP); fast path (49/64 blocks) has no clamps.
    // Phase 2: pack f32->f16, write LDS. One barrier total.
    float4 fv[NLD];
    const bool fastpath = (gx0 < 448) && (ybase32 < 448);
    if (fastpath) {
#pragma unroll
        for (int k = 0; k < NLD; ++k) {
            int t = tid + 256 * k;
            if (k < NLD - 1 || t < 3200) {
                int chunk = t % 20;
                int sub = t / 20;          // 0..159
                int row = sub >> 1;        // 0..79
                const float* src = (sub & 1) ? db : rb;
                fv[k] = *reinterpret_cast<const float4*>(
                    src + (long)(ybase32 + row) * 512 + gx0 + 4 * chunk);
            }
        }
    } else {
#pragma unroll
        for (int k = 0; k < NLD; ++k) {
            int t = tid + 256 * k;
            if (k < NLD - 1 || t < 3200) {
                int chunk = t % 20;
                int sub = t / 20;
                int row = sub >> 1;
                int gy = ybase32 + row; if (gy > 511) gy = 511;
                int gxc = gx0 + 4 * chunk; if (gxc > 508) gxc = 508;
                const float* src = (sub & 1) ? db : rb;
                fv[k] = *reinterpret_cast<const float4*>(src + (long)gy * 512 + gxc);
            }
        }
    }
#pragma unroll
    for (int k = 0; k < NLD; ++k) {
        int t = tid + 256 * k;
        if (k < NLD - 1 || t < 3200) {
            int chunk = t % 20;
            int sub = t / 20;
            int row = sub >> 1;
            _Float16* dstp = ((sub & 1) ? sd : sr) + row * SSTR + chunk * 4;
            union { fp16x2 h2[2]; uint2 u; } pk;
            pk.h2[0] = __builtin_amdgcn_cvt_pkrtz(fv[k].x, fv[k].y);
            pk.h2[1] = __builtin_amdgcn_cvt_pkrtz(fv[k].z, fv[k].w);
            *reinterpret_cast<uint2*>(dstp) = pk.u;
        }
    }
    __syncthreads();

    float lsum = 0.f;
    const int ox = gx0 + 16 * nt + ln;

#pragma unroll
    for (int it = 0; it < 2; ++it) {
        // ---- horizontal conv: ONE 16x16x32 MFMA per quantity per row-tile ----
        f16x4 hf0[4], hf1[4], hf2[4];
#define COMP_H(HF, MT)                                                        \
        {                                                                     \
            f32x4 z = {0, 0, 0, 0};                                           \
            int rrow = ln + 16 * (MT) + 32 * it;                              \
            const f16x8 rA = *(const f16x8*)(sr + rrow * SSTR + 16 * nt + 8 * g); \
            const f16x8 dA = *(const f16x8*)(sd + rrow * SSTR + 16 * nt + 8 * g); \
            f16x8 sA = rA + dA, qA = rA - dA;                                 \
            f16x8 ss = sA * sA, qq = qA * qA;                                 \
            f32x4 a0 = __builtin_amdgcn_mfma_f32_16x16x32_f16(rA, wh, z, 0, 0, 0); \
            f32x4 a1 = __builtin_amdgcn_mfma_f32_16x16x32_f16(dA, wh, z, 0, 0, 0); \
            f32x4 a2 = __builtin_amdgcn_mfma_f32_16x16x32_f16(ss, wh, z, 0, 0, 0); \
            f32x4 a3 = __builtin_amdgcn_mfma_f32_16x16x32_f16(qq, wh, z, 0, 0, 0); \
            HF[0] = cvt4(a0); HF[1] = cvt4(a1); HF[2] = cvt4(a2); HF[3] = cvt4(a3); \
        }
        COMP_H(hf0, 0)
        COMP_H(hf1, 1)
        COMP_H(hf2, 2)
#undef COMP_H

        // ---- vertical conv (2x 16x16x16, register B-frags) + f32x2 epilogue ----
#define COMP_O(HA, HB, MTV)                                                   \
        {                                                                     \
            f32x4 z = {0, 0, 0, 0};                                           \
            f32x4 v0 = __builtin_amdgcn_mfma_f32_16x16x16f16(wf0, HA[0], z, 0, 0, 0); \
            f32x4 v1 = __builtin_amdgcn_mfma_f32_16x16x16f16(wf0, HA[1], z, 0, 0, 0); \
            f32x4 v2 = __builtin_amdgcn_mfma_f32_16x16x16f16(wf0, HA[2], z, 0, 0, 0); \
            f32x4 v3 = __builtin_amdgcn_mfma_f32_16x16x16f16(wf0, HA[3], z, 0, 0, 0); \
            v0 = __builtin_amdgcn_mfma_f32_16x16x16f16(wf1, HB[0], v0, 0, 0, 0); \
            v1 = __builtin_amdgcn_mfma_f32_16x16x16f16(wf1, HB[1], v1, 0, 0, 0); \
            v2 = __builtin_amdgcn_mfma_f32_16x16x16f16(wf1, HB[2], v2, 0, 0, 0); \
            v3 = __builtin_amdgcn_mfma_f32_16x16x16f16(wf1, HB[3], v3, 0, 0, 0); \
            int oy0 = ybase32 + 32 * it + 16 * (MTV) + 4 * g;                 \
            if (ox < 502) {                                                   \
                _Pragma("unroll")                                             \
                for (int p = 0; p < 2; ++p) {                                 \
                    f32x2 m1 = {v0[2*p], v0[2*p+1]};                          \
                    f32x2 m2 = {v1[2*p], v1[2*p+1]};                          \
                    f32x2 A  = {v2[2*p], v2[2*p+1]};                          \
                    f32x2 B  = {v3[2*p], v3[2*p+1]};                          \
                    f32x2 m1s = m1 * m1, m2s = m2 * m2, m12 = m1 * m2;        \
                    f32x2 P = m1s + m2s;                                      \
                    f32x2 num1 = 2.f * m12 + 6.5025f;                         \
                    f32x2 num2 = 0.5f * (A - B) - 2.f * m12 + 58.5225f;       \
                    f32x2 den1 = P + 6.5025f;                                 \
                    f32x2 den2 = 0.5f * (A + B) - P + 58.5225f;               \
                    f32x2 num = num1 * num2, den = den1 * den2;               \
                    if (oy0 + 2*p     < 502) lsum += __fdividef(num[0], den[0]); \
                    if (oy0 + 2*p + 1 < 502) lsum += __fdividef(num[1], den[1]); \
                }                                                             \
            }                                                                 \
        }
        COMP_O(hf0, hf1, 0)
        COMP_O(hf1, hf2, 1)
#undef COMP_O
    }

    // per-wave reduce + scattered atomic (no fences, no extra barrier)
#pragma unroll
    for (int off = 32; off; off >>= 1) lsum += __shfl_down(lsum, off);
    if (lane == 0) {
        int bucket = ((blockIdx.x + (blockIdx.y << 3) + blockIdx.z * 67) * 4 + wv) & (NBUCKETS - 1);
        atomicAdd(&buckets[bucket], lsum);
    }
}

__global__ void ssim_finalize(const float* __restrict__ buckets,
                              float* __restrict__ out, float inv)
{
    int t = threadIdx.x;
    float s = 0.f;
    for (int i = t; i < NBUCKETS; i += 64) s += buckets[i];
#pragma unroll
    for (int off = 32; off; off >>= 1) s += __shfl_down(s, off);
    if (t == 0) out[0] = s * inv;
}

extern "C" void kernel_launch(void* const* d_in, const int* in_sizes, int n_in,
                              void* d_out, int out_size, void* d_ws, size_t ws_size,
                              hipStream_t stream) {
    const float* raw = (const float*)d_in[0];
    const float* dst = (const float*)d_in[1];
    const float* win = (const float*)d_in[2];
    float* out = (float*)d_out;
    float* ws = (float*)d_ws;

    int nimg = in_sizes[0] / (512 * 512);     // B*C = 48
    float inv = 1.0f / ((float)nimg * 502.f * 502.f);

    ssim_pre<<<1, 64, 0, stream>>>(win, ws);
    dim3 grid(8, 8, nimg);                    // 64-wide x-tile, 64-tall y-region, image
    ssim_main<<<grid, 256, 0, stream>>>(raw, dst, ws, ws);
    ssim_finalize<<<1, 64, 0, stream>>>(ws, out, inv);
}